// Round 11
// baseline (59.540 us; speedup 1.0000x reference)
//
#include <hip/hip_runtime.h>
#include <hip/hip_fp16.h>

typedef _Float16 h2 __attribute__((ext_vector_type(2)));

constexpr int Bc  = 4;
constexpr int Cc  = 64;
constexpr int H0  = 128;
constexpr int W0  = 128;
constexpr int HW  = H0 * W0;
constexpr int Gc  = 4;
constexpr int HOc = H0 * 2;      // 256
constexpr int WOc = W0 * 2;      // 256

constexpr int TW = 16;           // output tile width
constexpr int TH = 8;            // output tile height
constexpr int HX = TW + 2;       // 18 halo cols
constexpr int HY = TH + 2;       // 10 halo rows
constexpr int NHALO = HX * HY;   // 180
constexpr int NTASK = Gc * NHALO;// 720

constexpr int SXC = 10;          // staged input cols (ox/2-1 .. ox/2+8)
constexpr int SYC = 6;           // staged input rows (oy/2-1 .. oy/2+4)
constexpr int SN  = SXC * SYC;   // 60 positions per channel
constexpr int NPAIR = Cc / 2;    // 32 channel pairs
constexpr int NSTG  = NPAIR * SN;// 1920 u32 per tile stage

union hu32 { unsigned u; h2 h; };

__device__ __forceinline__ float dot2(h2 a, unsigned bw, float c) {
    hu32 cv; cv.u = bw;
#if __has_builtin(__builtin_amdgcn_fdot2)
    return __builtin_amdgcn_fdot2(a, cv.h, c, false);
#else
    return fmaf((float)a[0], (float)cv.h[0],
                fmaf((float)a[1], (float)cv.h[1], c));
#endif
}

// ---------------------------------------------------------------------------
// kT: prep packed weights in ws (unchanged).
// ---------------------------------------------------------------------------
__global__ __launch_bounds__(256) void kT_prep(
    const float* __restrict__ w_off, const float* __restrict__ w_offm,
    const float* __restrict__ w_sk,  const float* __restrict__ w_km,
    __half2* __restrict__ wpk0, __half2* __restrict__ wpk)
{
    const int i = blockIdx.x * 256 + threadIdx.x;
    if (i < 2048) {
        const int c2  = i >> 6;
        const int rem = i & 63;
        const int mat = rem >> 5;
        const int r   = rem & 31;
        const float* src = mat ? w_offm : w_off;
        wpk0[i] = __floats2half2_rn(src[r * Cc + 2 * c2],
                                    src[r * Cc + 2 * c2 + 1]);
    } else if (i < 2048 + 576) {
        const int j   = i - 2048;
        const int mat = j >= 288;
        const int jj  = mat ? j - 288 : j;
        const int k   = jj >> 5;
        const int c2  = jj & 31;
        const float* src = mat ? w_km : w_sk;
        wpk[j] = __floats2half2_rn(src[k * Cc + 2 * c2],
                                   src[k * Cc + 2 * c2 + 1]);
    }
}

// ---------------------------------------------------------------------------
// k0 v7: gated offset conv + x transpose, COALESCED stores via padded LDS.
// Block = 64 px x 4 row-split waves. Wave w computes rows [w*8,w*8+8) via
// fdot2 with wave-uniform packed weights (s_load). All outputs staged in LDS
// (pad +1 to kill bank conflicts), then written as contiguous 1KB bursts.
// ---------------------------------------------------------------------------
__global__ __launch_bounds__(256) void k0_offsets(
    const float* __restrict__ x, const unsigned* __restrict__ wpk0,
    const float* __restrict__ b_off, const float* __restrict__ b_offm,
    unsigned* __restrict__ offbuf, unsigned* __restrict__ xt)
{
    __shared__ unsigned xt_lds[64 * 33];   // [px][c2] pad33 (8448 B)
    __shared__ unsigned ob_lds[64 * 17];   // [px][rp] pad17 (4352 B)

    const int b    = blockIdx.y;
    const int t    = threadIdx.x;
    const int wave = t >> 6, lane = t & 63;
    const int r0   = __builtin_amdgcn_readfirstlane(wave * 8);
    const int px   = blockIdx.x * 64 + lane;

    float a[8], m[8];
#pragma unroll
    for (int q = 0; q < 8; ++q) { a[q] = 0.f; m[q] = 0.f; }

    const float*    xp = x + (size_t)b * Cc * HW + px;
    const unsigned* wp = wpk0 + r0;      // wave-uniform base

#pragma unroll 4
    for (int c2 = 0; c2 < NPAIR; ++c2) {
        const float x0 = xp[(2 * c2)     * HW];   // coalesced 256B
        const float x1 = xp[(2 * c2 + 1) * HW];
        hu32 xh; xh.h = h2{(_Float16)x0, (_Float16)x1};
        if (wave == 0) xt_lds[lane * 33 + c2] = xh.u;
#pragma unroll
        for (int q = 0; q < 8; ++q) {
            a[q] = dot2(xh.h, wp[c2 * 64 + q],      a[q]);  // s_load weights
            m[q] = dot2(xh.h, wp[c2 * 64 + 32 + q], m[q]);
        }
    }

#pragma unroll
    for (int j = 0; j < 4; ++j) {
        const int r = r0 + 2 * j;
        const float sx = 1.f / (1.f + __expf(-(m[2 * j]     + b_offm[r])));
        const float sy = 1.f / (1.f + __expf(-(m[2 * j + 1] + b_offm[r + 1])));
        const float vx = (a[2 * j]     + b_off[r])     * sx;
        const float vy = (a[2 * j + 1] + b_off[r + 1]) * sy;
        const __half2 hh = __floats2half2_rn(vx, vy);
        union { __half2 h; unsigned u; } cv; cv.h = hh;
        ob_lds[lane * 17 + (r0 >> 1) + j] = cv.u;
    }
    __syncthreads();

    // coalesced copy-out: xt (2048 u32) and offbuf (1024 u32)
    unsigned* xo = xt + ((size_t)b * HW + blockIdx.x * 64) * NPAIR;
#pragma unroll
    for (int it = 0; it < 8; ++it) {
        const int idx = it * 256 + t;                 // px_local*32 + c2
        xo[idx] = xt_lds[(idx >> 5) * 33 + (idx & 31)];
    }
    unsigned* oo = offbuf + ((size_t)b * HW + blockIdx.x * 64) * 16;
#pragma unroll
    for (int it = 0; it < 4; ++it) {
        const int idx = it * 256 + t;                 // px_local*16 + rp
        oo[idx] = ob_lds[(idx >> 4) * 17 + (idx & 15)];
    }
}

// ---------------------------------------------------------------------------
// k1_fused v3: persistent 2-tile blocks with cross-tile T14 prefetch of BOTH
// the stage data AND the per-task offset words (o2p regs). LDS 37632 B ->
// 4 blocks/CU; grid 1024 = exact residency.
// ---------------------------------------------------------------------------
__global__ __launch_bounds__(256) void k1_fused(
    const unsigned* __restrict__ xt, const unsigned* __restrict__ offbuf,
    const unsigned* __restrict__ wsku, const float* __restrict__ b_sk,
    const float* __restrict__ b_km,
    float* __restrict__ out)
{
    __shared__ h2       xd2[NPAIR][NHALO];   // 23040 B: deformed halo
    __shared__ unsigned xs_u[NSTG];          //  7680 B: stage (u32 = h2 pair)
    __shared__ unsigned short kmbh[128 * 9]; //  2304 B: km logits fp16
    __shared__ unsigned sknb[128 * 9];       //  4608 B: softmax splat h2

    const unsigned* wkmu = wsku + 288;

    const int b    = blockIdx.y;
    const int tp   = blockIdx.x;           // 16 x-tiles * 16 y-pairs
    const int ox = (tp & 15) * TW;
    const int oyb = (tp >> 4) * (2 * TH);  // y-pair base
    const int t  = threadIdx.x;
    const int sxr = (ox >> 1) - 1;
    const int syr0 = (oyb >> 1) - 1;       // tile0 window origin rows
    const int syr1 = syr0 + (TH >> 1);     // tile1: +4 rows

    const unsigned* xtb = xt + (size_t)b * HW * NPAIR;
    const unsigned* obu = offbuf + (size_t)b * HW * 16;

    // ---- prologue: issue BOTH tiles' stage loads + offset words ----
    unsigned pre0[8], pre1[8];
#pragma unroll
    for (int k = 0; k < 8; ++k) {
        const int i = t + k * 256;
        if (i < NSTG) {
            const int c2  = i & 31;
            const int pos = i >> 5;
            const int r   = pos / SXC;
            const int j   = pos - r * SXC;
            const int xx  = min(max(sxr + j, 0), W0 - 1);
            const int yy0 = min(max(syr0 + r, 0), H0 - 1);
            const int yy1 = min(max(syr1 + r, 0), H0 - 1);
            pre0[k] = xtb[(yy0 * W0 + xx) * NPAIR + c2];
            pre1[k] = xtb[(yy1 * W0 + xx) * NPAIR + c2];
        }
    }
    unsigned o2p0[3] = {0u, 0u, 0u}, o2p1[3] = {0u, 0u, 0u};
#pragma unroll
    for (int it = 0; it < 3; ++it) {
        const int task = t + it * 256;
        if (task < NTASK) {
            const int g   = task / NHALO;
            const int pix = task - g * NHALO;
            const int hy  = pix / HX;
            const int hx  = pix - hy * HX;
            const int gx  = ox - 1 + hx;
            const int gy0 = oyb - 1 + hy;
            const int gy1 = gy0 + TH;
            if (gx >= 0 && gx < WOc) {
                const int w = gx >> 1, sxb = gx & 1;
                if (gy0 >= 0 && gy0 < HOc)
                    o2p0[it] = obu[((gy0 >> 1) * W0 + w) * 16
                                   + g * 4 + (gy0 & 1) * 2 + sxb];
                if (gy1 < HOc)
                    o2p1[it] = obu[((gy1 >> 1) * W0 + w) * 16
                                   + g * 4 + (gy1 & 1) * 2 + sxb];
            }
        }
    }
#pragma unroll
    for (int k = 0; k < 8; ++k) {
        const int i = t + k * 256;
        if (i < NSTG) {
            const int c2 = i & 31, pos = i >> 5;
            xs_u[c2 * SN + pos] = pre0[k];
        }
    }
    __syncthreads();

    for (int yt = 0; yt < 2; ++yt) {
        const int oy  = oyb + yt * TH;
        const int syr = yt ? syr1 : syr0;
        const h2* xstage2 = (const h2*)xs_u;

        // ---- phase B: pk bilinear -> xd2 (offsets from prefetched regs) ----
#pragma unroll
        for (int it = 0; it < 3; ++it) {
            const int task = t + it * 256;
            if (task >= NTASK) continue;
            const int g   = task / NHALO;
            const int pix = task - g * NHALO;
            const int hy  = pix / HX;
            const int hx  = pix - hy * HX;
            const int gy  = oy - 1 + hy;
            const int gx  = ox - 1 + hx;
            if (gy < 0 || gy >= HOc || gx < 0 || gx >= WOc) {
#pragma unroll
                for (int p = 0; p < 8; ++p) xd2[g * 8 + p][pix] = (h2)0;
                continue;
            }
            hu32 o2u; o2u.u = yt ? o2p1[it] : o2p0[it];
            const float offx = (float)o2u.h[0];
            const float offy = (float)o2u.h[1];

            float ix = ((float)gx + 0.5f + offx) * 0.5f - 0.5f;
            float iy = ((float)gy + 0.5f + offy) * 0.5f - 0.5f;
            ix = fminf(fmaxf(ix, 0.f), (float)(W0 - 1));
            iy = fminf(fmaxf(iy, 0.f), (float)(H0 - 1));
            const float x0f = floorf(ix), y0f = floorf(iy);
            const float wx = ix - x0f,   wy = iy - y0f;
            const int x0 = (int)x0f, y0 = (int)y0f;
            const int x1 = min(x0 + 1, W0 - 1), y1 = min(y0 + 1, H0 - 1);
            const float w00 = (1.f - wx) * (1.f - wy);
            const float w01 = wx * (1.f - wy);
            const float w10 = (1.f - wx) * wy;
            const float w11 = wx * wy;

            const int j0 = x0 - sxr, j1 = x1 - sxr;
            const int i0 = y0 - syr, i1 = y1 - syr;
            const bool inl = (j0 >= 0) & (j1 < SXC) & (i0 >= 0) & (i1 < SYC);

            const _Float16 W00 = (_Float16)w00, W01 = (_Float16)w01;
            const _Float16 W10 = (_Float16)w10, W11 = (_Float16)w11;

            if (inl) {
                const int o00 = i0 * SXC + j0, o01 = i0 * SXC + j1;
                const int o10 = i1 * SXC + j0, o11 = i1 * SXC + j1;
                const h2* s2 = xstage2 + (g * 8) * SN;
#pragma unroll
                for (int p = 0; p < 8; ++p) {
                    const h2* pc = s2 + p * SN;
                    xd2[g * 8 + p][pix] =
                        pc[o00] * W00 + pc[o01] * W01 + pc[o10] * W10 + pc[o11] * W11;
                }
            } else {  // rare: tap escaped staged window -> global x_t
                const int o00 = (y0 * W0 + x0) * NPAIR, o01 = (y0 * W0 + x1) * NPAIR;
                const int o10 = (y1 * W0 + x0) * NPAIR, o11 = (y1 * W0 + x1) * NPAIR;
#pragma unroll
                for (int p = 0; p < 8; ++p) {
                    const int c2 = g * 8 + p;
                    hu32 v00, v01, v10, v11;
                    v00.u = xtb[o00 + c2]; v01.u = xtb[o01 + c2];
                    v10.u = xtb[o10 + c2]; v11.u = xtb[o11 + c2];
                    xd2[c2][pix] =
                        v00.h * W00 + v01.h * W01 + v10.h * W10 + v11.h * W11;
                }
            }
        }
        __syncthreads();

        // ---- tile1 stage write: xstage is dead now; hide under C/D ----
        if (yt == 0) {
#pragma unroll
            for (int k = 0; k < 8; ++k) {
                const int i = t + k * 256;
                if (i < NSTG) {
                    const int c2 = i & 31, pos = i >> 5;
                    xs_u[c2 * SN + pos] = pre1[k];
                }
            }
        }

        // ---- phase C: reg-cached xv + fdot2, gate + softmax -> sknb ----
        {
            const int p   = t & 127;
            const int ctr = ((p >> 4) + 1) * HX + (p & 15) + 1;
            h2 xv[NPAIR];
#pragma unroll
            for (int c2 = 0; c2 < NPAIR; ++c2) xv[c2] = xd2[c2][ctr];

            float acc[9];
            if (t < 128) {
#pragma unroll
                for (int k = 0; k < 9; ++k) {
                    float a = 0.f;
#pragma unroll
                    for (int c2 = 0; c2 < NPAIR; ++c2)
                        a = dot2(xv[c2], wsku[k * 32 + c2], a);   // s_load
                    acc[k] = a;
                }
            } else {
#pragma unroll
                for (int k = 0; k < 9; ++k) {
                    float a = 0.f;
#pragma unroll
                    for (int c2 = 0; c2 < NPAIR; ++c2)
                        a = dot2(xv[c2], wkmu[k * 32 + c2], a);
                    kmbh[p * 9 + k] = __half_as_ushort(__float2half(a));
                }
            }
            __syncthreads();

            if (t < 128) {
                float sv[9], mx = -1e30f;
#pragma unroll
                for (int k = 0; k < 9; ++k) {
                    const float z = __half2float(__ushort_as_half(kmbh[p * 9 + k]))
                                    + b_km[k];
                    sv[k] = (acc[k] + b_sk[k]) / (1.f + __expf(-z));
                    mx = fmaxf(mx, sv[k]);
                }
                float sum = 0.f;
#pragma unroll
                for (int k = 0; k < 9; ++k) { sv[k] = __expf(sv[k] - mx); sum += sv[k]; }
                const float inv = 1.f / sum;
#pragma unroll
                for (int k = 0; k < 9; ++k) {
                    const unsigned hu = __half_as_ushort(__float2half(sv[k] * inv));
                    sknb[p * 9 + k] = hu | (hu << 16);            // splat h2
                }
            }
        }
        __syncthreads();

        // ---- phase D: 3x3 dynamic conv, pk math ----
        {
            const int sq    = t & 31;
            const int chunk = t >> 5;          // 8 chunks x 4 pairs
            const int sqx = sq & 7, sqy = sq >> 3;
            const int hx0 = 2 * sqx, hy0 = 2 * sqy;
            const int p00 = (2 * sqy) * TW + 2 * sqx;

            hu32 s00[9], s01[9], s10[9], s11[9];
#pragma unroll
            for (int k = 0; k < 9; ++k) {
                s00[k].u = sknb[p00 * 9 + k];        s01[k].u = sknb[(p00 + 1) * 9 + k];
                s10[k].u = sknb[(p00 + TW) * 9 + k]; s11[k].u = sknb[(p00 + TW + 1) * 9 + k];
            }
            const int orow0 = oy + 2 * sqy, ocol0 = ox + 2 * sqx;

#pragma unroll
            for (int i = 0; i < 4; ++i) {
                const int pr = chunk * 4 + i;
                h2 wd[4][4];
#pragma unroll
                for (int ry = 0; ry < 4; ++ry) {
                    const int base = (hy0 + ry) * HX + hx0;
#pragma unroll
                    for (int rx = 0; rx < 4; ++rx)
                        wd[ry][rx] = xd2[pr][base + rx];
                }
                h2 a00 = (h2)0, a01 = (h2)0, a10 = (h2)0, a11 = (h2)0;
#pragma unroll
                for (int ky = 0; ky < 3; ++ky)
#pragma unroll
                    for (int kx = 0; kx < 3; ++kx) {
                        const int k = ky * 3 + kx;
                        a00 += s00[k].h * wd[ky    ][kx    ];
                        a01 += s01[k].h * wd[ky    ][kx + 1];
                        a10 += s10[k].h * wd[ky + 1][kx    ];
                        a11 += s11[k].h * wd[ky + 1][kx + 1];
                    }
                float* ob0 = out + ((size_t)(b * Cc + 2 * pr)) * (HOc * WOc)
                                 + (size_t)orow0 * WOc + ocol0;
                float* ob1 = ob0 + (size_t)(HOc * WOc);
                *reinterpret_cast<float2*>(ob0)       = make_float2((float)a00[0], (float)a01[0]);
                *reinterpret_cast<float2*>(ob0 + WOc) = make_float2((float)a10[0], (float)a11[0]);
                *reinterpret_cast<float2*>(ob1)       = make_float2((float)a00[1], (float)a01[1]);
                *reinterpret_cast<float2*>(ob1 + WOc) = make_float2((float)a10[1], (float)a11[1]);
            }
        }
        __syncthreads();   // xd2/xstage WAR before next tile's phase B
    }
}

// ---------------------------------------------------------------------------
extern "C" void kernel_launch(void* const* d_in, const int* in_sizes, int n_in,
                              void* d_out, int out_size, void* d_ws, size_t ws_size,
                              hipStream_t stream)
{
    const float* x      = (const float*)d_in[0];
    const float* w_off  = (const float*)d_in[1];
    const float* b_off  = (const float*)d_in[2];
    const float* w_offm = (const float*)d_in[3];
    const float* b_offm = (const float*)d_in[4];
    const float* w_sk   = (const float*)d_in[5];
    const float* b_sk   = (const float*)d_in[6];
    const float* w_km   = (const float*)d_in[7];
    const float* b_km   = (const float*)d_in[8];
    float* outp = (float*)d_out;

    const size_t off_bytes  = (size_t)Bc * HW * 16 * sizeof(unsigned);    // 4 MiB
    const size_t xt_bytes   = (size_t)Bc * HW * NPAIR * sizeof(unsigned); // 8 MiB
    const size_t wpk0_bytes = 2048 * sizeof(__half2);
    const size_t wpk_bytes  = 576 * sizeof(__half2);
    if (ws_size < off_bytes + xt_bytes + wpk0_bytes + wpk_bytes) return;
    unsigned* offbuf = (unsigned*)d_ws;
    unsigned* xtbuf  = (unsigned*)((char*)d_ws + off_bytes);
    __half2*  wpk0   = (__half2*)((char*)d_ws + off_bytes + xt_bytes);
    __half2*  wpk    = (__half2*)((char*)d_ws + off_bytes + xt_bytes + wpk0_bytes);

    dim3 blk(256);
    hipLaunchKernelGGL(kT_prep, dim3(11), blk, 0, stream,
                       w_off, w_offm, w_sk, w_km, wpk0, wpk);

    dim3 g0(HW / 64, Bc);                 // 1024 blocks: 64 px x 4 row-waves
    hipLaunchKernelGGL(k0_offsets, g0, blk, 0, stream,
                       x, (const unsigned*)wpk0, b_off, b_offm, offbuf, xtbuf);

    dim3 g1(256, Bc);                     // 16x16 y-pair tiles x b — NO swizzle
    hipLaunchKernelGGL(k1_fused, g1, blk, 0, stream,
                       xtbuf, offbuf, (const unsigned*)wpk, b_sk, b_km, outp);
}

// Round 12
// 54.826 us; speedup vs baseline: 1.0860x; 1.0860x over previous
//
#include <hip/hip_runtime.h>
#include <hip/hip_fp16.h>

typedef _Float16 h2 __attribute__((ext_vector_type(2)));

constexpr int Bc  = 4;
constexpr int Cc  = 64;
constexpr int H0  = 128;
constexpr int W0  = 128;
constexpr int HW  = H0 * W0;
constexpr int Gc  = 4;
constexpr int HOc = H0 * 2;      // 256
constexpr int WOc = W0 * 2;      // 256

constexpr int TW = 16;           // output tile width
constexpr int TH = 8;            // output tile height
constexpr int HX = TW + 2;       // 18 halo cols
constexpr int HY = TH + 2;       // 10 halo rows
constexpr int NHALO = HX * HY;   // 180
constexpr int NTASK = Gc * NHALO;// 720

constexpr int SXC = 10;          // staged input cols (ox/2-1 .. ox/2+8)
constexpr int SYC = 6;           // staged input rows (oy/2-1 .. oy/2+4)
constexpr int SN  = SXC * SYC;   // 60 positions per channel
constexpr int NPAIR = Cc / 2;    // 32 channel pairs
constexpr int NSTG  = NPAIR * SN;// 1920 u32 per tile stage

union hu32 { unsigned u; h2 h; };

__device__ __forceinline__ float dot2(h2 a, unsigned bw, float c) {
    hu32 cv; cv.u = bw;
#if __has_builtin(__builtin_amdgcn_fdot2)
    return __builtin_amdgcn_fdot2(a, cv.h, c, false);
#else
    return fmaf((float)a[0], (float)cv.h[0],
                fmaf((float)a[1], (float)cv.h[1], c));
#endif
}

// ---------------------------------------------------------------------------
// kT: prep packed weights in ws (unchanged).
// ---------------------------------------------------------------------------
__global__ __launch_bounds__(256) void kT_prep(
    const float* __restrict__ w_off, const float* __restrict__ w_offm,
    const float* __restrict__ w_sk,  const float* __restrict__ w_km,
    __half2* __restrict__ wpk0, __half2* __restrict__ wpk)
{
    const int i = blockIdx.x * 256 + threadIdx.x;
    if (i < 2048) {
        const int c2  = i >> 6;
        const int rem = i & 63;
        const int mat = rem >> 5;
        const int r   = rem & 31;
        const float* src = mat ? w_offm : w_off;
        wpk0[i] = __floats2half2_rn(src[r * Cc + 2 * c2],
                                    src[r * Cc + 2 * c2 + 1]);
    } else if (i < 2048 + 576) {
        const int j   = i - 2048;
        const int mat = j >= 288;
        const int jj  = mat ? j - 288 : j;
        const int k   = jj >> 5;
        const int c2  = jj & 31;
        const float* src = mat ? w_km : w_sk;
        wpk[j] = __floats2half2_rn(src[k * Cc + 2 * c2],
                                   src[k * Cc + 2 * c2 + 1]);
    }
}

// ---------------------------------------------------------------------------
// k0 v7 (kept from round 11): gated offset conv + x transpose, coalesced
// stores via padded LDS staging.
// ---------------------------------------------------------------------------
__global__ __launch_bounds__(256) void k0_offsets(
    const float* __restrict__ x, const unsigned* __restrict__ wpk0,
    const float* __restrict__ b_off, const float* __restrict__ b_offm,
    unsigned* __restrict__ offbuf, unsigned* __restrict__ xt)
{
    __shared__ unsigned xt_lds[64 * 33];   // [px][c2] pad33 (8448 B)
    __shared__ unsigned ob_lds[64 * 17];   // [px][rp] pad17 (4352 B)

    const int b    = blockIdx.y;
    const int t    = threadIdx.x;
    const int wave = t >> 6, lane = t & 63;
    const int r0   = __builtin_amdgcn_readfirstlane(wave * 8);
    const int px   = blockIdx.x * 64 + lane;

    float a[8], m[8];
#pragma unroll
    for (int q = 0; q < 8; ++q) { a[q] = 0.f; m[q] = 0.f; }

    const float*    xp = x + (size_t)b * Cc * HW + px;
    const unsigned* wp = wpk0 + r0;      // wave-uniform base

#pragma unroll 4
    for (int c2 = 0; c2 < NPAIR; ++c2) {
        const float x0 = xp[(2 * c2)     * HW];   // coalesced 256B
        const float x1 = xp[(2 * c2 + 1) * HW];
        hu32 xh; xh.h = h2{(_Float16)x0, (_Float16)x1};
        if (wave == 0) xt_lds[lane * 33 + c2] = xh.u;
#pragma unroll
        for (int q = 0; q < 8; ++q) {
            a[q] = dot2(xh.h, wp[c2 * 64 + q],      a[q]);  // s_load weights
            m[q] = dot2(xh.h, wp[c2 * 64 + 32 + q], m[q]);
        }
    }

#pragma unroll
    for (int j = 0; j < 4; ++j) {
        const int r = r0 + 2 * j;
        const float sx = 1.f / (1.f + __expf(-(m[2 * j]     + b_offm[r])));
        const float sy = 1.f / (1.f + __expf(-(m[2 * j + 1] + b_offm[r + 1])));
        const float vx = (a[2 * j]     + b_off[r])     * sx;
        const float vy = (a[2 * j + 1] + b_off[r + 1]) * sy;
        const __half2 hh = __floats2half2_rn(vx, vy);
        union { __half2 h; unsigned u; } cv; cv.h = hh;
        ob_lds[lane * 17 + (r0 >> 1) + j] = cv.u;
    }
    __syncthreads();

    // coalesced copy-out: xt (2048 u32) and offbuf (1024 u32)
    unsigned* xo = xt + ((size_t)b * HW + blockIdx.x * 64) * NPAIR;
#pragma unroll
    for (int it = 0; it < 8; ++it) {
        const int idx = it * 256 + t;                 // px_local*32 + c2
        xo[idx] = xt_lds[(idx >> 5) * 33 + (idx & 31)];
    }
    unsigned* oo = offbuf + ((size_t)b * HW + blockIdx.x * 64) * 16;
#pragma unroll
    for (int it = 0; it < 4; ++it) {
        const int idx = it * 256 + t;                 // px_local*16 + rp
        oo[idx] = ob_lds[(idx >> 4) * 17 + (idx & 15)];
    }
}

// ---------------------------------------------------------------------------
// k1_fused: EXACT round-10 structure (measured 55.4 us total): rolled phase-B
// loop, in-loop offset loads, cross-tile stage prefetch only.
// ---------------------------------------------------------------------------
__global__ __launch_bounds__(256) void k1_fused(
    const unsigned* __restrict__ xt, const unsigned* __restrict__ offbuf,
    const unsigned* __restrict__ wsku, const float* __restrict__ b_sk,
    const float* __restrict__ b_km,
    float* __restrict__ out)
{
    __shared__ h2       xd2[NPAIR][NHALO];   // 23040 B: deformed halo
    __shared__ unsigned xs_u[NSTG];          //  7680 B: stage (u32 = h2 pair)
    __shared__ unsigned short kmbh[128 * 9]; //  2304 B: km logits fp16
    __shared__ unsigned sknb[128 * 9];       //  4608 B: softmax splat h2

    const unsigned* wkmu = wsku + 288;

    const int b    = blockIdx.y;
    const int tp   = blockIdx.x;           // 16 x-tiles * 16 y-pairs
    const int ox = (tp & 15) * TW;
    const int oyb = (tp >> 4) * (2 * TH);  // y-pair base
    const int t  = threadIdx.x;
    const int sxr = (ox >> 1) - 1;
    const int syr0 = (oyb >> 1) - 1;       // tile0 window origin rows
    const int syr1 = syr0 + (TH >> 1);     // tile1: +4 rows

    const unsigned* xtb = xt + (size_t)b * HW * NPAIR;
    const unsigned* obu = offbuf + (size_t)b * HW * 16;

    // ---- prologue: issue BOTH tiles' stage loads into registers ----
    unsigned pre0[8], pre1[8];
#pragma unroll
    for (int k = 0; k < 8; ++k) {
        const int i = t + k * 256;
        if (i < NSTG) {
            const int c2  = i & 31;
            const int pos = i >> 5;
            const int r   = pos / SXC;
            const int j   = pos - r * SXC;
            const int xx  = min(max(sxr + j, 0), W0 - 1);
            const int yy0 = min(max(syr0 + r, 0), H0 - 1);
            const int yy1 = min(max(syr1 + r, 0), H0 - 1);
            pre0[k] = xtb[(yy0 * W0 + xx) * NPAIR + c2];
            pre1[k] = xtb[(yy1 * W0 + xx) * NPAIR + c2];
        }
    }
#pragma unroll
    for (int k = 0; k < 8; ++k) {
        const int i = t + k * 256;
        if (i < NSTG) {
            const int c2 = i & 31, pos = i >> 5;
            xs_u[c2 * SN + pos] = pre0[k];
        }
    }
    __syncthreads();

    for (int yt = 0; yt < 2; ++yt) {
        const int oy  = oyb + yt * TH;
        const int syr = yt ? syr1 : syr0;
        const h2* xstage2 = (const h2*)xs_u;

        // ---- phase B: pk bilinear -> xd2 (rolled loop, in-loop offsets) ----
        for (int task = t; task < NTASK; task += 256) {
            const int g   = task / NHALO;
            const int pix = task - g * NHALO;
            const int hy  = pix / HX;
            const int hx  = pix - hy * HX;
            const int gy  = oy - 1 + hy;
            const int gx  = ox - 1 + hx;
            if (gy < 0 || gy >= HOc || gx < 0 || gx >= WOc) {
#pragma unroll
                for (int p = 0; p < 8; ++p) xd2[g * 8 + p][pix] = (h2)0;
                continue;
            }
            const int sy = gy & 1, sx = gx & 1;
            const int h  = gy >> 1, w  = gx >> 1;
            hu32 o2u; o2u.u = obu[(size_t)(h * W0 + w) * 16 + g * 4 + sy * 2 + sx];
            const float offx = (float)o2u.h[0];
            const float offy = (float)o2u.h[1];

            float ix = ((float)gx + 0.5f + offx) * 0.5f - 0.5f;
            float iy = ((float)gy + 0.5f + offy) * 0.5f - 0.5f;
            ix = fminf(fmaxf(ix, 0.f), (float)(W0 - 1));
            iy = fminf(fmaxf(iy, 0.f), (float)(H0 - 1));
            const float x0f = floorf(ix), y0f = floorf(iy);
            const float wx = ix - x0f,   wy = iy - y0f;
            const int x0 = (int)x0f, y0 = (int)y0f;
            const int x1 = min(x0 + 1, W0 - 1), y1 = min(y0 + 1, H0 - 1);
            const float w00 = (1.f - wx) * (1.f - wy);
            const float w01 = wx * (1.f - wy);
            const float w10 = (1.f - wx) * wy;
            const float w11 = wx * wy;

            const int j0 = x0 - sxr, j1 = x1 - sxr;
            const int i0 = y0 - syr, i1 = y1 - syr;
            const bool inl = (j0 >= 0) & (j1 < SXC) & (i0 >= 0) & (i1 < SYC);

            const _Float16 W00 = (_Float16)w00, W01 = (_Float16)w01;
            const _Float16 W10 = (_Float16)w10, W11 = (_Float16)w11;

            if (inl) {
                const int o00 = i0 * SXC + j0, o01 = i0 * SXC + j1;
                const int o10 = i1 * SXC + j0, o11 = i1 * SXC + j1;
                const h2* s2 = xstage2 + (g * 8) * SN;
#pragma unroll
                for (int p = 0; p < 8; ++p) {
                    const h2* pc = s2 + p * SN;
                    xd2[g * 8 + p][pix] =
                        pc[o00] * W00 + pc[o01] * W01 + pc[o10] * W10 + pc[o11] * W11;
                }
            } else {  // rare: tap escaped staged window -> global x_t
                const int o00 = (y0 * W0 + x0) * NPAIR, o01 = (y0 * W0 + x1) * NPAIR;
                const int o10 = (y1 * W0 + x0) * NPAIR, o11 = (y1 * W0 + x1) * NPAIR;
#pragma unroll
                for (int p = 0; p < 8; ++p) {
                    const int c2 = g * 8 + p;
                    hu32 v00, v01, v10, v11;
                    v00.u = xtb[o00 + c2]; v01.u = xtb[o01 + c2];
                    v10.u = xtb[o10 + c2]; v11.u = xtb[o11 + c2];
                    xd2[c2][pix] =
                        v00.h * W00 + v01.h * W01 + v10.h * W10 + v11.h * W11;
                }
            }
        }
        __syncthreads();

        // ---- tile1 stage write: xstage is dead now; hide under C/D ----
        if (yt == 0) {
#pragma unroll
            for (int k = 0; k < 8; ++k) {
                const int i = t + k * 256;
                if (i < NSTG) {
                    const int c2 = i & 31, pos = i >> 5;
                    xs_u[c2 * SN + pos] = pre1[k];
                }
            }
        }

        // ---- phase C: reg-cached xv + fdot2, gate + softmax -> sknb ----
        {
            const int p   = t & 127;
            const int ctr = ((p >> 4) + 1) * HX + (p & 15) + 1;
            h2 xv[NPAIR];
#pragma unroll
            for (int c2 = 0; c2 < NPAIR; ++c2) xv[c2] = xd2[c2][ctr];

            float acc[9];
            if (t < 128) {
#pragma unroll
                for (int k = 0; k < 9; ++k) {
                    float a = 0.f;
#pragma unroll
                    for (int c2 = 0; c2 < NPAIR; ++c2)
                        a = dot2(xv[c2], wsku[k * 32 + c2], a);   // s_load
                    acc[k] = a;
                }
            } else {
#pragma unroll
                for (int k = 0; k < 9; ++k) {
                    float a = 0.f;
#pragma unroll
                    for (int c2 = 0; c2 < NPAIR; ++c2)
                        a = dot2(xv[c2], wkmu[k * 32 + c2], a);
                    kmbh[p * 9 + k] = __half_as_ushort(__float2half(a));
                }
            }
            __syncthreads();

            if (t < 128) {
                float sv[9], mx = -1e30f;
#pragma unroll
                for (int k = 0; k < 9; ++k) {
                    const float z = __half2float(__ushort_as_half(kmbh[p * 9 + k]))
                                    + b_km[k];
                    sv[k] = (acc[k] + b_sk[k]) / (1.f + __expf(-z));
                    mx = fmaxf(mx, sv[k]);
                }
                float sum = 0.f;
#pragma unroll
                for (int k = 0; k < 9; ++k) { sv[k] = __expf(sv[k] - mx); sum += sv[k]; }
                const float inv = 1.f / sum;
#pragma unroll
                for (int k = 0; k < 9; ++k) {
                    const unsigned hu = __half_as_ushort(__float2half(sv[k] * inv));
                    sknb[p * 9 + k] = hu | (hu << 16);            // splat h2
                }
            }
        }
        __syncthreads();

        // ---- phase D: 3x3 dynamic conv, pk math ----
        {
            const int sq    = t & 31;
            const int chunk = t >> 5;          // 8 chunks x 4 pairs
            const int sqx = sq & 7, sqy = sq >> 3;
            const int hx0 = 2 * sqx, hy0 = 2 * sqy;
            const int p00 = (2 * sqy) * TW + 2 * sqx;

            hu32 s00[9], s01[9], s10[9], s11[9];
#pragma unroll
            for (int k = 0; k < 9; ++k) {
                s00[k].u = sknb[p00 * 9 + k];        s01[k].u = sknb[(p00 + 1) * 9 + k];
                s10[k].u = sknb[(p00 + TW) * 9 + k]; s11[k].u = sknb[(p00 + TW + 1) * 9 + k];
            }
            const int orow0 = oy + 2 * sqy, ocol0 = ox + 2 * sqx;

#pragma unroll
            for (int i = 0; i < 4; ++i) {
                const int pr = chunk * 4 + i;
                h2 wd[4][4];
#pragma unroll
                for (int ry = 0; ry < 4; ++ry) {
                    const int base = (hy0 + ry) * HX + hx0;
#pragma unroll
                    for (int rx = 0; rx < 4; ++rx)
                        wd[ry][rx] = xd2[pr][base + rx];
                }
                h2 a00 = (h2)0, a01 = (h2)0, a10 = (h2)0, a11 = (h2)0;
#pragma unroll
                for (int ky = 0; ky < 3; ++ky)
#pragma unroll
                    for (int kx = 0; kx < 3; ++kx) {
                        const int k = ky * 3 + kx;
                        a00 += s00[k].h * wd[ky    ][kx    ];
                        a01 += s01[k].h * wd[ky    ][kx + 1];
                        a10 += s10[k].h * wd[ky + 1][kx    ];
                        a11 += s11[k].h * wd[ky + 1][kx + 1];
                    }
                float* ob0 = out + ((size_t)(b * Cc + 2 * pr)) * (HOc * WOc)
                                 + (size_t)orow0 * WOc + ocol0;
                float* ob1 = ob0 + (size_t)(HOc * WOc);
                *reinterpret_cast<float2*>(ob0)       = make_float2((float)a00[0], (float)a01[0]);
                *reinterpret_cast<float2*>(ob0 + WOc) = make_float2((float)a10[0], (float)a11[0]);
                *reinterpret_cast<float2*>(ob1)       = make_float2((float)a00[1], (float)a01[1]);
                *reinterpret_cast<float2*>(ob1 + WOc) = make_float2((float)a10[1], (float)a11[1]);
            }
        }
        __syncthreads();   // xd2/xstage WAR before next tile's phase B
    }
}

// ---------------------------------------------------------------------------
extern "C" void kernel_launch(void* const* d_in, const int* in_sizes, int n_in,
                              void* d_out, int out_size, void* d_ws, size_t ws_size,
                              hipStream_t stream)
{
    const float* x      = (const float*)d_in[0];
    const float* w_off  = (const float*)d_in[1];
    const float* b_off  = (const float*)d_in[2];
    const float* w_offm = (const float*)d_in[3];
    const float* b_offm = (const float*)d_in[4];
    const float* w_sk   = (const float*)d_in[5];
    const float* b_sk   = (const float*)d_in[6];
    const float* w_km   = (const float*)d_in[7];
    const float* b_km   = (const float*)d_in[8];
    float* outp = (float*)d_out;

    const size_t off_bytes  = (size_t)Bc * HW * 16 * sizeof(unsigned);    // 4 MiB
    const size_t xt_bytes   = (size_t)Bc * HW * NPAIR * sizeof(unsigned); // 8 MiB
    const size_t wpk0_bytes = 2048 * sizeof(__half2);
    const size_t wpk_bytes  = 576 * sizeof(__half2);
    if (ws_size < off_bytes + xt_bytes + wpk0_bytes + wpk_bytes) return;
    unsigned* offbuf = (unsigned*)d_ws;
    unsigned* xtbuf  = (unsigned*)((char*)d_ws + off_bytes);
    __half2*  wpk0   = (__half2*)((char*)d_ws + off_bytes + xt_bytes);
    __half2*  wpk    = (__half2*)((char*)d_ws + off_bytes + xt_bytes + wpk0_bytes);

    dim3 blk(256);
    hipLaunchKernelGGL(kT_prep, dim3(11), blk, 0, stream,
                       w_off, w_offm, w_sk, w_km, wpk0, wpk);

    dim3 g0(HW / 64, Bc);                 // 1024 blocks: 64 px x 4 row-waves
    hipLaunchKernelGGL(k0_offsets, g0, blk, 0, stream,
                       x, (const unsigned*)wpk0, b_off, b_offm, offbuf, xtbuf);

    dim3 g1(256, Bc);                     // 16x16 y-pair tiles x b — NO swizzle
    hipLaunchKernelGGL(k1_fused, g1, blk, 0, stream,
                       xtbuf, offbuf, (const unsigned*)wpk, b_sk, b_km, outp);
}